// Round 4
// baseline (592.258 us; speedup 1.0000x reference)
//
#include <hip/hip_runtime.h>
#include <stdint.h>

// GridEncoder (instant-ngp hash grid), D=3, L=16, C=2, H=16, PLS=2, log2_hash=19.
// Round 4:
//  - 4 points/thread, ALL 32 gathers issued before any consume (round-3 had
//    VGPR=28 -> compiler ran a ~5-deep load pipe; latency-bound at ~90
//    outstanding lines/CU). Deep arrays force ~24-32 loads in flight/wave.
//  - XCD-affinity remap: assuming round-robin blockIdx->XCD, XCD k handles
//    levels {k, 15-k} only -> each 4MB table slice is fetched by ONE XCD's L2
//    (round-3 FETCH=594MB showed all 8 XCDs refetching every slice).
//  - interleave pass unchanged (coalesced both sides, ~35us, near roofline).
// Numerics identical to rounds 1-3 (no fma contraction of x*scale+0.5).

#define NLEV 16

__constant__ uint32_t dOff[NLEV] = {
    0u, 4096u, 36864u, 299008u, 823296u, 1347584u, 1871872u, 2396160u,
    2920448u, 3444736u, 3969024u, 4493312u, 5017600u, 5541888u,
    6066176u, 6590464u };
__constant__ uint32_t dMask[NLEV] = {
    4095u, 32767u, 262143u, 524287u, 524287u, 524287u, 524287u, 524287u,
    524287u, 524287u, 524287u, 524287u, 524287u, 524287u, 524287u, 524287u };
__constant__ float dScale[NLEV] = {
    15.f, 31.f, 63.f, 127.f, 255.f, 511.f, 1023.f, 2047.f,
    4095.f, 8191.f, 16383.f, 32767.f, 65535.f, 131071.f, 262143.f, 524287.f };

constexpr uint32_t P1 = 2654435761u, P2 = 805459861u;

// rows + fractional parts only (weights expanded at consume time, same
// multiplication order as rounds 1-3: w = wx * (wy * wz))
__device__ __forceinline__ void encode_rows(
    float x, float y, float z, float scale, uint32_t mask, uint32_t off,
    uint32_t rows[8], float f[3])
{
    const float px = __fadd_rn(__fmul_rn(x, scale), 0.5f);
    const float py = __fadd_rn(__fmul_rn(y, scale), 0.5f);
    const float pz = __fadd_rn(__fmul_rn(z, scale), 0.5f);
    const float fx0 = floorf(px), fy0 = floorf(py), fz0 = floorf(pz);
    const uint32_t X0 = (uint32_t)fx0;
    const uint32_t Y0 = (uint32_t)fy0;
    const uint32_t Z0 = (uint32_t)fz0;
    f[0] = px - fx0; f[1] = py - fy0; f[2] = pz - fz0;

    const uint32_t hx0 = X0,      hx1 = X0 + 1u;
    const uint32_t hy0 = Y0 * P1, hy1 = hy0 + P1;
    const uint32_t hz0 = Z0 * P2, hz1 = hz0 + P2;

    rows[0] = ((hx0 ^ hy0 ^ hz0) & mask) + off;
    rows[1] = ((hx1 ^ hy0 ^ hz0) & mask) + off;
    rows[2] = ((hx0 ^ hy1 ^ hz0) & mask) + off;
    rows[3] = ((hx1 ^ hy1 ^ hz0) & mask) + off;
    rows[4] = ((hx0 ^ hy0 ^ hz1) & mask) + off;
    rows[5] = ((hx1 ^ hy0 ^ hz1) & mask) + off;
    rows[6] = ((hx0 ^ hy1 ^ hz1) & mask) + off;
    rows[7] = ((hx1 ^ hy1 ^ hz1) & mask) + off;
}

__device__ __forceinline__ void expand_weights(const float f[3], float w[8])
{
    const float wx1 = f[0], wx0 = 1.0f - f[0];
    const float wy1 = f[1], wy0 = 1.0f - f[1];
    const float wz1 = f[2], wz0 = 1.0f - f[2];
    const float wy0z0 = wy0 * wz0, wy1z0 = wy1 * wz0;
    const float wy0z1 = wy0 * wz1, wy1z1 = wy1 * wz1;
    w[0] = wx0 * wy0z0; w[1] = wx1 * wy0z0;
    w[2] = wx0 * wy1z0; w[3] = wx1 * wy1z0;
    w[4] = wx0 * wy0z1; w[5] = wx1 * wy0z1;
    w[6] = wx0 * wy1z1; w[7] = wx1 * wy1z1;
}

// 4 points per thread; XCD-affinity level assignment.
// grid.x = 16 * bpl blocks; block g -> xcd = g&7 (round-robin assumption),
// j = g>>3 in [0, 2*bpl): level = (j<bpl) ? xcd : 15-xcd.
__global__ __launch_bounds__(256, 6) void levels_fused4_kernel(
    const float* __restrict__ inp,   // [B,3]
    const float2* __restrict__ etab, // [total_rows]
    float2* __restrict__ slab,       // [NLEV][B]
    int B, int bpl)
{
    const uint32_t g = blockIdx.x;
    const uint32_t xcd = g & 7u;
    const uint32_t j = g >> 3;
    const int lvl = (j < (uint32_t)bpl) ? (int)xcd : (int)(15u - xcd);
    const uint32_t xb = (j < (uint32_t)bpl) ? j : (j - (uint32_t)bpl);

    const float    scale = dScale[lvl];
    const uint32_t mask  = dMask[lvl];
    const uint32_t off   = dOff[lvl];
    float2* __restrict__ lslab = slab + (size_t)lvl * B;

    const int q = B >> 2;
    const int t = (int)(xb * 256u + threadIdx.x);
    if (t >= q) return;

    uint32_t rows[4][8];
    float f[4][3];
    #pragma unroll
    for (int p = 0; p < 4; ++p) {
        const int b = t + p * q;
        const float x = (inp[3 * b + 0] + 1.0f) * 0.5f;
        const float y = (inp[3 * b + 1] + 1.0f) * 0.5f;
        const float z = (inp[3 * b + 2] + 1.0f) * 0.5f;
        encode_rows(x, y, z, scale, mask, off, rows[p], f[p]);
    }

    // issue ALL 32 gathers before consuming anything (deep MLP)
    float2 e[4][8];
    #pragma unroll
    for (int p = 0; p < 4; ++p) {
        #pragma unroll
        for (int c = 0; c < 8; ++c) e[p][c] = etab[rows[p][c]];
    }

    #pragma unroll
    for (int p = 0; p < 4; ++p) {
        float w[8];
        expand_weights(f[p], w);
        float ax = 0.f, ay = 0.f;
        #pragma unroll
        for (int c = 0; c < 8; ++c) {
            ax = fmaf(w[c], e[p][c].x, ax);
            ay = fmaf(w[c], e[p][c].y, ay);
        }
        lslab[t + p * q] = make_float2(ax, ay);
    }
}

// ws [L][B] float2 (level-major) -> out [B][8] float4 (level-interleaved)
__global__ __launch_bounds__(256) void interleave_kernel(
    const float2* __restrict__ ws, float4* __restrict__ out, int B)
{
    const int g = blockIdx.x * blockDim.x + threadIdx.x;
    if (g >= B * 8) return;
    const int p = g >> 3;
    const int c = g & 7;
    const float2 v0 = ws[(size_t)(2 * c)     * B + p];
    const float2 v1 = ws[(size_t)(2 * c + 1) * B + p];
    out[g] = make_float4(v0.x, v0.y, v1.x, v1.y);
}

// ---------------- fallback: round-1 flat kernel (proven correct) -----------
__global__ __launch_bounds__(256) void grid_encode_flat(
    const float* __restrict__ inp, const float* __restrict__ emb,
    float* __restrict__ out, int B)
{
    const int b = blockIdx.x * blockDim.x + threadIdx.x;
    if (b >= B) return;
    const float x = (inp[3 * b + 0] + 1.0f) * 0.5f;
    const float y = (inp[3 * b + 1] + 1.0f) * 0.5f;
    const float z = (inp[3 * b + 2] + 1.0f) * 0.5f;
    const float2* etab = (const float2*)emb;
    float res[2 * NLEV];
    #pragma unroll
    for (int l = 0; l < NLEV; ++l) {
        uint32_t rows[8]; float fr[3], wts[8];
        encode_rows(x, y, z, dScale[l], dMask[l], dOff[l], rows, fr);
        expand_weights(fr, wts);
        float2 e[8];
        #pragma unroll
        for (int c = 0; c < 8; ++c) e[c] = etab[rows[c]];
        float ax = 0.f, ay = 0.f;
        #pragma unroll
        for (int c = 0; c < 8; ++c) { ax = fmaf(wts[c], e[c].x, ax); ay = fmaf(wts[c], e[c].y, ay); }
        res[2 * l + 0] = ax; res[2 * l + 1] = ay;
    }
    float4* o4 = (float4*)(out + (size_t)b * (2 * NLEV));
    #pragma unroll
    for (int k = 0; k < 8; ++k)
        o4[k] = make_float4(res[4 * k + 0], res[4 * k + 1], res[4 * k + 2], res[4 * k + 3]);
}

extern "C" void kernel_launch(void* const* d_in, const int* in_sizes, int n_in,
                              void* d_out, int out_size, void* d_ws, size_t ws_size,
                              hipStream_t stream) {
    const float* inp = (const float*)d_in[0];   // [B,3] float32
    const float* emb = (const float*)d_in[1];   // [total_rows,2] float32
    float* out = (float*)d_out;                 // [B,32] float32
    const int B = in_sizes[0] / 3;

    const size_t need = (size_t)B * NLEV * 2 * sizeof(float);
    if (ws_size >= need && (B & 3) == 0) {
        float2* ws = (float2*)d_ws;
        const float2* etab = (const float2*)emb;
        const int q = B >> 2;
        const int bpl = (q + 255) / 256;         // blocks per level
        dim3 gridL(16 * bpl);
        levels_fused4_kernel<<<gridL, 256, 0, stream>>>(inp, etab, ws, B, bpl);
        const int blkI = (B * 8 + 255) / 256;
        interleave_kernel<<<blkI, 256, 0, stream>>>(ws, (float4*)out, B);
    } else {
        const int blk = (B + 255) / 256;
        grid_encode_flat<<<blk, 256, 0, stream>>>(inp, emb, out, B);
    }
}

// Round 5
// 552.509 us; speedup vs baseline: 1.0719x; 1.0719x over previous
//
#include <hip/hip_runtime.h>
#include <stdint.h>

// GridEncoder (instant-ngp hash grid), D=3, L=16, C=2, H=16, PLS=2, log2_hash=19.
// Round 5: revert to round-3 structure (best: 500us gather phase) —
//   2 pts/thread, blockIdx.y = level, NO XCD remap (round 4 showed the remap
//   causes XCD load imbalance: +11%; each XCD already replicates the current
//   level's <=4MB slice in its local L2, so affinity buys nothing).
// New single variable: NON-TEMPORAL gathers for levels >= 2. L1 hit rate at
// those levels is ~1% (32KB L1 vs >=2MB slices), so every gather pays TCP
// line-allocate+evict for nothing; nt bypasses that. Levels 0-1 keep normal
// loads (level-0 rows are re-read ~8x per CU -> real L1 hits).
// Numerics identical to rounds 1-4 (no fma contraction of x*scale+0.5).

#define NLEV 16

__constant__ uint32_t dOff[NLEV] = {
    0u, 4096u, 36864u, 299008u, 823296u, 1347584u, 1871872u, 2396160u,
    2920448u, 3444736u, 3969024u, 4493312u, 5017600u, 5541888u,
    6066176u, 6590464u };
__constant__ uint32_t dMask[NLEV] = {
    4095u, 32767u, 262143u, 524287u, 524287u, 524287u, 524287u, 524287u,
    524287u, 524287u, 524287u, 524287u, 524287u, 524287u, 524287u, 524287u };
__constant__ float dScale[NLEV] = {
    15.f, 31.f, 63.f, 127.f, 255.f, 511.f, 1023.f, 2047.f,
    4095.f, 8191.f, 16383.f, 32767.f, 65535.f, 131071.f, 262143.f, 524287.f };

constexpr uint32_t P1 = 2654435761u, P2 = 805459861u;

__device__ __forceinline__ float2 ld_nt(const float2* p) {
    // single 8B non-temporal load (avoid scalarization into two dwords)
    double d = __builtin_nontemporal_load(reinterpret_cast<const double*>(p));
    return __builtin_bit_cast(float2, d);
}

__device__ __forceinline__ void encode_point(
    float x, float y, float z, float scale, uint32_t mask, uint32_t off,
    uint32_t rows[8], float ws[8])
{
    const float px = __fadd_rn(__fmul_rn(x, scale), 0.5f);
    const float py = __fadd_rn(__fmul_rn(y, scale), 0.5f);
    const float pz = __fadd_rn(__fmul_rn(z, scale), 0.5f);
    const float fx0 = floorf(px), fy0 = floorf(py), fz0 = floorf(pz);
    const uint32_t X0 = (uint32_t)fx0;
    const uint32_t Y0 = (uint32_t)fy0;
    const uint32_t Z0 = (uint32_t)fz0;
    const float fx = px - fx0, fy = py - fy0, fz = pz - fz0;

    const uint32_t hx0 = X0,      hx1 = X0 + 1u;
    const uint32_t hy0 = Y0 * P1, hy1 = hy0 + P1;
    const uint32_t hz0 = Z0 * P2, hz1 = hz0 + P2;

    rows[0] = ((hx0 ^ hy0 ^ hz0) & mask) + off;
    rows[1] = ((hx1 ^ hy0 ^ hz0) & mask) + off;
    rows[2] = ((hx0 ^ hy1 ^ hz0) & mask) + off;
    rows[3] = ((hx1 ^ hy1 ^ hz0) & mask) + off;
    rows[4] = ((hx0 ^ hy0 ^ hz1) & mask) + off;
    rows[5] = ((hx1 ^ hy0 ^ hz1) & mask) + off;
    rows[6] = ((hx0 ^ hy1 ^ hz1) & mask) + off;
    rows[7] = ((hx1 ^ hy1 ^ hz1) & mask) + off;

    const float wx1 = fx, wx0 = 1.0f - fx;
    const float wy1 = fy, wy0 = 1.0f - fy;
    const float wz1 = fz, wz0 = 1.0f - fz;
    const float wy0z0 = wy0 * wz0, wy1z0 = wy1 * wz0;
    const float wy0z1 = wy0 * wz1, wy1z1 = wy1 * wz1;
    ws[0] = wx0 * wy0z0; ws[1] = wx1 * wy0z0;
    ws[2] = wx0 * wy1z0; ws[3] = wx1 * wy1z0;
    ws[4] = wx0 * wy0z1; ws[5] = wx1 * wy0z1;
    ws[6] = wx0 * wy1z1; ws[7] = wx1 * wy1z1;
}

// all levels in one dispatch: blockIdx.y = level; two points per thread
__global__ __launch_bounds__(256, 8) void levels_fused_kernel(
    const float* __restrict__ inp,   // [B,3]
    const float2* __restrict__ etab, // [total_rows]
    float2* __restrict__ slab,       // [NLEV][B]
    int B)
{
    const int lvl = blockIdx.y;
    const float    scale = dScale[lvl];
    const uint32_t mask  = dMask[lvl];
    const uint32_t off   = dOff[lvl];
    float2* __restrict__ lslab = slab + (size_t)lvl * B;

    const int t = blockIdx.x * blockDim.x + threadIdx.x;
    const int half = B >> 1;
    if (t >= half) return;
    const int b0 = t, b1 = t + half;

    const float x0 = (inp[3 * b0 + 0] + 1.0f) * 0.5f;
    const float y0 = (inp[3 * b0 + 1] + 1.0f) * 0.5f;
    const float z0 = (inp[3 * b0 + 2] + 1.0f) * 0.5f;
    const float x1 = (inp[3 * b1 + 0] + 1.0f) * 0.5f;
    const float y1 = (inp[3 * b1 + 1] + 1.0f) * 0.5f;
    const float z1 = (inp[3 * b1 + 2] + 1.0f) * 0.5f;

    uint32_t r0[8], r1[8];
    float w0[8], w1[8];
    encode_point(x0, y0, z0, scale, mask, off, r0, w0);
    encode_point(x1, y1, z1, scale, mask, off, r1, w1);

    float2 e0[8], e1[8];
    if (mask > 32767u) {
        // levels 2-15: table slice >= 2MB, L1 useless -> non-temporal
        #pragma unroll
        for (int c = 0; c < 8; ++c) e0[c] = ld_nt(&etab[r0[c]]);
        #pragma unroll
        for (int c = 0; c < 8; ++c) e1[c] = ld_nt(&etab[r1[c]]);
    } else {
        #pragma unroll
        for (int c = 0; c < 8; ++c) e0[c] = etab[r0[c]];
        #pragma unroll
        for (int c = 0; c < 8; ++c) e1[c] = etab[r1[c]];
    }

    float a0x = 0.f, a0y = 0.f, a1x = 0.f, a1y = 0.f;
    #pragma unroll
    for (int c = 0; c < 8; ++c) {
        a0x = fmaf(w0[c], e0[c].x, a0x);
        a0y = fmaf(w0[c], e0[c].y, a0y);
        a1x = fmaf(w1[c], e1[c].x, a1x);
        a1y = fmaf(w1[c], e1[c].y, a1y);
    }
    lslab[b0] = make_float2(a0x, a0y);
    lslab[b1] = make_float2(a1x, a1y);
}

// ws [L][B] float2 (level-major) -> out [B][8] float4 (level-interleaved)
// chunk-per-thread: thread g writes exactly one float4 (fully coalesced)
__global__ __launch_bounds__(256) void interleave_kernel(
    const float2* __restrict__ ws, float4* __restrict__ out, int B)
{
    const int g = blockIdx.x * blockDim.x + threadIdx.x;
    if (g >= B * 8) return;
    const int p = g >> 3;        // point
    const int c = g & 7;         // float4 chunk = levels (2c, 2c+1)
    const float2 v0 = ws[(size_t)(2 * c)     * B + p];
    const float2 v1 = ws[(size_t)(2 * c + 1) * B + p];
    out[g] = make_float4(v0.x, v0.y, v1.x, v1.y);
}

// ---------------- fallback: round-1 flat kernel (proven correct) -----------
__global__ __launch_bounds__(256) void grid_encode_flat(
    const float* __restrict__ inp, const float* __restrict__ emb,
    float* __restrict__ out, int B)
{
    const int b = blockIdx.x * blockDim.x + threadIdx.x;
    if (b >= B) return;
    const float x = (inp[3 * b + 0] + 1.0f) * 0.5f;
    const float y = (inp[3 * b + 1] + 1.0f) * 0.5f;
    const float z = (inp[3 * b + 2] + 1.0f) * 0.5f;
    const float2* etab = (const float2*)emb;
    float res[2 * NLEV];
    #pragma unroll
    for (int l = 0; l < NLEV; ++l) {
        uint32_t rows[8]; float wts[8];
        encode_point(x, y, z, dScale[l], dMask[l], dOff[l], rows, wts);
        float2 e[8];
        #pragma unroll
        for (int c = 0; c < 8; ++c) e[c] = etab[rows[c]];
        float ax = 0.f, ay = 0.f;
        #pragma unroll
        for (int c = 0; c < 8; ++c) { ax = fmaf(wts[c], e[c].x, ax); ay = fmaf(wts[c], e[c].y, ay); }
        res[2 * l + 0] = ax; res[2 * l + 1] = ay;
    }
    float4* o4 = (float4*)(out + (size_t)b * (2 * NLEV));
    #pragma unroll
    for (int k = 0; k < 8; ++k)
        o4[k] = make_float4(res[4 * k + 0], res[4 * k + 1], res[4 * k + 2], res[4 * k + 3]);
}

extern "C" void kernel_launch(void* const* d_in, const int* in_sizes, int n_in,
                              void* d_out, int out_size, void* d_ws, size_t ws_size,
                              hipStream_t stream) {
    const float* inp = (const float*)d_in[0];   // [B,3] float32
    const float* emb = (const float*)d_in[1];   // [total_rows,2] float32
    float* out = (float*)d_out;                 // [B,32] float32
    const int B = in_sizes[0] / 3;

    const size_t need = (size_t)B * NLEV * 2 * sizeof(float);
    if (ws_size >= need && (B & 1) == 0) {
        float2* ws = (float2*)d_ws;
        const float2* etab = (const float2*)emb;
        const int half = B >> 1;
        dim3 gridL((half + 255) / 256, NLEV);
        levels_fused_kernel<<<gridL, 256, 0, stream>>>(inp, etab, ws, B);
        const int blkI = (B * 8 + 255) / 256;
        interleave_kernel<<<blkI, 256, 0, stream>>>(ws, (float4*)out, B);
    } else {
        const int blk = (B + 255) / 256;
        grid_encode_flat<<<blk, 256, 0, stream>>>(inp, emb, out, B);
    }
}